// Round 10
// baseline (320.118 us; speedup 1.0000x reference)
//
#include <hip/hip_runtime.h>

// ---------------- problem constants ----------------
#define B_     32
#define C_     2
#define L_     160000
#define HOP    512
#define PAD    1024
#define LPAD   162048            // L_ + 2*PAD
#define T_     313               // frames
#define BC     64                // B_*C_
#define M_     20032             // BC*T_
#define KCH    1025              // output channels per (real|imag)
#define OUT_HALF 20532800UL      // M_*KCH
#define PL     81024             // plane length per bc (LPAD/2)
#define KD     1024              // decimated K
#define NKT    32                // KD/32 K-tiles
#define MTP    160               // M tiles padded to 8*20 (157 real)
#define NWG    1280              // MTP*8
#define LIMW   8336              // im word offset: 128*65+16

typedef __attribute__((ext_vector_type(8))) short short8;
typedef __attribute__((ext_vector_type(4))) float f32x4;

static __device__ __forceinline__ short f2bf(float f) {
  union { float f; unsigned u; } v; v.f = f;
  unsigned u = v.u;
  unsigned r = (u + 0x7fffu + ((u >> 16) & 1u)) >> 16;  // RNE
  return (short)r;
}

// ---------------- prep 1: even/odd deinterleaved reflect-padded planes ----------------
__global__ void prep_planes(const float* __restrict__ x,
                            short* __restrict__ pl0, short* __restrict__ pl1) {
  int v = blockIdx.x * 256 + threadIdx.x;           // < 64*10128 = 648192
  int bc = v / 10128;
  int r  = v - bc * 10128;
  int p0 = r * 8;                                   // 8 p-positions -> 16 samples
  const float* src = x + (size_t)bc * L_;
  short8 e, o;
  if (r >= 64 && r <= 10000) {                      // fully interior
    int j0 = 16 * r - 1024;
    #pragma unroll
    for (int qq = 0; qq < 4; ++qq) {
      float4 f = *(const float4*)(src + j0 + qq * 4);
      e[qq * 2 + 0] = f2bf(f.x); o[qq * 2 + 0] = f2bf(f.y);
      e[qq * 2 + 1] = f2bf(f.z); o[qq * 2 + 1] = f2bf(f.w);
    }
  } else {
    #pragma unroll
    for (int u = 0; u < 16; ++u) {
      int j = 16 * r + u - 1024;
      j = j < 0 ? -j : j;
      j = j >= L_ ? 2 * L_ - 2 - j : j;
      short b = f2bf(src[j]);
      if (u & 1) o[u >> 1] = b; else e[u >> 1] = b;
    }
  }
  *(short8*)&pl0[(size_t)bc * PL + p0] = e;
  *(short8*)&pl1[(size_t)bc * PL + p0] = o;
}

// ---------------- prep 2: windowed DFT-1024 weights, interleaved re/im rows ----------------
__global__ void prep_wb(short* __restrict__ wb0, short* __restrict__ wb1) {
  int id = blockIdx.x * 256 + threadIdx.x;          // < 2*1024*128 = 262144
  int s   = id >> 17;
  int row = (id >> 7) & 1023;
  int n8  = (id & 127) * 8;
  int kp  = row >> 1, e = row & 1;
  short8 ov;
  #pragma unroll
  for (int u = 0; u < 8; ++u) {
    int n1 = n8 + u;
    float win = 0.5f - 0.5f * cosf((float)(2 * n1 + s) * 3.0679615757712823e-3f); // pi/1024
    float tw;
    if (e == 0)       tw = cosf((float)((n1 * kp) & 1023) * 6.1359231515425649e-3f); // 2pi/1024
    else if (kp == 0) tw = (n1 & 1) ? -1.0f : 1.0f;       // cos(pi*n1): re[512] row
    else              tw = -sinf((float)((n1 * kp) & 1023) * 6.1359231515425649e-3f);
    ov[u] = f2bf(win * tw);
  }
  short* wb = s ? wb1 : wb0;
  *(short8*)&wb[(size_t)row * KD + n8] = ov;
}

// ---------------- GEMM: direct-from-L2 register GEMM, no main-loop LDS ----------------
__global__ __launch_bounds__(512, 4) void stft_gemm(const short* __restrict__ pl0,
                                                    const short* __restrict__ pl1,
                                                    const short* __restrict__ wb0,
                                                    const short* __restrict__ wb1,
                                                    float* __restrict__ out) {
  // LDS used ONLY by the epilogue: lre[128][65] + pad + lim[128][65] fp32
  __shared__ __align__(16) char lds[66688];
  const int tid  = threadIdx.x;
  const int lane = tid & 63;
  const int wid  = tid >> 6;          // 0..7

  // ---- XCD remap: 8 nt-blocks sharing an A-panel are consecutive ids with the
  // same id%8 -> same XCD -> A panel + B stay L2-resident (FETCH 77MB, r7).
  const int id = blockIdx.x;                   // 0..1279
  const int mt = (id & 7) * 20 + (id >> 6);    // 0..159 (>=157 dead-padded)
  const int nt = (id >> 3) & 7;
  const int M0 = mt * 128, N0 = nt * 128;

  // ---- wave roles: sw = plane, (wm, wn) = 64x64 sub-tile ----
  const int sw = wid & 1, wn = (wid >> 1) & 1, wm = wid >> 2;

  // ---- per-lane direct fragment pointers (16B per lane, line-covered) ----
  // MFMA 16x16x32 operand map: row/col = lane&15, k = (lane>>4)*8 + j
  const int fr = lane & 15;
  const int kh = lane >> 4;                    // 0..3  -> k base kh*8
  const short* plS = sw ? pl1 : pl0;
  const short* wbS = sw ? wb1 : wb0;
  const short* aPtr[4];
  const short* bPtr[4];
  #pragma unroll
  for (int i = 0; i < 4; ++i) {
    int m = M0 + wm * 64 + i * 16 + fr;
    if (m > M_ - 1) m = M_ - 1;                // clamp tail (not stored)
    int bc = m / T_;
    int t  = m - bc * T_;
    aPtr[i] = plS + (size_t)bc * PL + (size_t)t * 256 + kh * 8;
  }
  #pragma unroll
  for (int j = 0; j < 4; ++j) {
    int n = N0 + wn * 64 + j * 16 + fr;        // < 1024 always
    bPtr[j] = wbS + (size_t)n * KD + kh * 8;
  }

  f32x4 acc[4][4];
  #pragma unroll
  for (int i = 0; i < 4; ++i)
    #pragma unroll
    for (int j = 0; j < 4; ++j) acc[i][j] = (f32x4){0.f, 0.f, 0.f, 0.f};

  // ---- main loop: 8 direct loads + 16 MFMA per K-tile; NO barriers, NO LDS ----
  for (int kt = 0; kt < NKT; ++kt) {
    const int ko = kt * 32;
    short8 af[4], bf[4];
    #pragma unroll
    for (int i = 0; i < 4; ++i) af[i] = *(const short8*)(aPtr[i] + ko);
    #pragma unroll
    for (int j = 0; j < 4; ++j) bf[j] = *(const short8*)(bPtr[j] + ko);
    __builtin_amdgcn_s_setprio(1);
    #pragma unroll
    for (int i = 0; i < 4; ++i)
      #pragma unroll
      for (int j = 0; j < 4; ++j)
        acc[i][j] = __builtin_amdgcn_mfma_f32_16x16x32_bf16(af[i], bf[j],
                                                            acc[i][j], 0, 0, 0);
    __builtin_amdgcn_s_setprio(0);
  }

  // ---- epilogue: cross-wave twiddle combine via LDS, coalesced writes ----
  // (byte-identical to round 9 — verified correct)
  float* L = (float*)lds;
  float* outI = out + OUT_HALF;
  const float PIQ = 3.0679615757712823e-3f;     // pi/1024
  const int rgrp = (lane >> 4) << 2;

  __syncthreads();

  #pragma unroll
  for (int pass = 0; pass < 2; ++pass) {
    if (sw == 0) {     // base term: +/- Y0
      #pragma unroll
      for (int j = 0; j < 4; ++j) {
        int c  = wn * 64 + j * 16 + fr;         // local col 0..127
        int q  = c >> 1;
        bool odd  = c & 1;
        bool spec = (nt == 0) && (c == 1);      // Y[512] special slot
        int widx = (odd ? LIMW : 0) + (pass ? (63 - q) : q);
        #pragma unroll
        for (int i = 0; i < 4; ++i) {
          int row = wm * 64 + i * 16 + rgrp;
          #pragma unroll
          for (int r = 0; r < 4; ++r) {
            float v0 = acc[i][j][r];
            float base = pass == 0 ? v0 : (odd ? -v0 : v0);
            if (spec) base = 0.f;
            L[widx + (row + r) * 65] = base;
            if (spec && pass == 0) {
              int gm = M0 + row + r;
              if (gm < M_) out[(size_t)gm * KCH + 512] = v0;   // X[512].re = Y0[512]
            }
          }
        }
      }
    }
    __syncthreads();
    if (sw == 1) {     // twiddle term: +/- t_q * Y1
      #pragma unroll
      for (int j = 0; j < 4; ++j) {
        int c  = wn * 64 + j * 16 + fr;
        int q  = c >> 1;
        float ang = (float)(nt * 64 + q) * PIQ;
        float tr = cosf(ang), sn = sinf(ang);
        bool odd  = c & 1;
        bool spec = (nt == 0) && (c == 1);
        float sgn = odd ? -sn : sn;
        int widx = (odd ? LIMW : 0) + (pass ? (63 - q) : q);
        #pragma unroll
        for (int i = 0; i < 4; ++i) {
          int row = wm * 64 + i * 16 + rgrp;
          #pragma unroll
          for (int r = 0; r < 4; ++r) {
            float v1 = acc[i][j][r];
            float p1 = __shfl_xor(v1, 1);
            float u  = tr * v1 + sgn * p1;
            if (!spec) {
              float addv = (pass == 0) ? u : (odd ? u : -u);
              int li = widx + (row + r) * 65;
              L[li] += addv;
            } else if (pass == 0) {
              int gm = M0 + row + r;
              if (gm < M_) outI[(size_t)gm * KCH + 512] = -v1; // X[512].im = -Y1[512]
            }
          }
        }
      }
    }
    __syncthreads();
    // coalesced write: each wave writes whole rows (64 consecutive floats)
    {
      int col0 = pass ? (1024 - nt * 64 - 63) : (nt * 64);
      #pragma unroll
      for (int i2 = 0; i2 < 16; ++i2) {
        int row = wid + i2 * 8;
        int gm  = M0 + row;
        if (gm < M_) {
          size_t rb = (size_t)gm * KCH + col0 + lane;
          out [rb] = L[row * 65 + lane];
          outI[rb] = L[LIMW + row * 65 + lane];
        }
      }
    }
    __syncthreads();   // arrays reused by next pass
  }
}

// ---------------- launcher ----------------
extern "C" void kernel_launch(void* const* d_in, const int* in_sizes, int n_in,
                              void* d_out, int out_size, void* d_ws, size_t ws_size,
                              hipStream_t stream) {
  const float* x = (const float*)d_in[0];
  float* out = (float*)d_out;

  short* pl0 = (short*)d_ws;                        // 64*81024 bf16
  short* pl1 = pl0 + (size_t)BC * PL;
  short* wb0 = pl1 + (size_t)BC * PL;               // 1024*1024
  short* wb1 = wb0 + (size_t)1024 * KD;             // total 24.9 MB

  prep_planes<<<2532, 256, 0, stream>>>(x, pl0, pl1);
  prep_wb<<<1024, 256, 0, stream>>>(wb0, wb1);

  stft_gemm<<<NWG, 512, 0, stream>>>(pl0, pl1, wb0, wb1, out);
}

// Round 11
// 151.090 us; speedup vs baseline: 2.1187x; 2.1187x over previous
//
#include <hip/hip_runtime.h>

// ---------------- problem constants ----------------
#define B_     32
#define C_     2
#define L_     160000
#define T_     313               // frames
#define BC     64                // B_*C_
#define M_     20032             // BC*T_
#define KCH    1025              // output channels per (real|imag)
#define OUT_HALF 20532800UL      // M_*KCH
#define PL     81024             // plane length per bc
#define KD     1024              // decimated K
#define NKT    32                // K-tiles (BK=32)
#define NWG    640               // 80 mt (79 live) x 8 nt
#define SLOT   49152             // 48KB per K-tile slot
#define IMBASE 16640             // float idx of im staging array (256*65)

typedef __attribute__((ext_vector_type(8))) short short8;
typedef __attribute__((ext_vector_type(4))) float f32x4;

static __device__ __forceinline__ short f2bf(float f) {
  union { float f; unsigned u; } v; v.f = f;
  unsigned u = v.u;
  unsigned r = (u + 0x7fffu + ((u >> 16) & 1u)) >> 16;  // RNE
  return (short)r;
}

// ---------------- prep 1: even/odd deinterleaved reflect-padded planes ----------------
__global__ void prep_planes(const float* __restrict__ x,
                            short* __restrict__ pl0, short* __restrict__ pl1) {
  int v = blockIdx.x * 256 + threadIdx.x;           // < 64*10128 = 648192
  int bc = v / 10128;
  int r  = v - bc * 10128;
  int p0 = r * 8;
  const float* src = x + (size_t)bc * L_;
  short8 e, o;
  if (r >= 64 && r <= 10000) {
    int j0 = 16 * r - 1024;
    #pragma unroll
    for (int qq = 0; qq < 4; ++qq) {
      float4 f = *(const float4*)(src + j0 + qq * 4);
      e[qq * 2 + 0] = f2bf(f.x); o[qq * 2 + 0] = f2bf(f.y);
      e[qq * 2 + 1] = f2bf(f.z); o[qq * 2 + 1] = f2bf(f.w);
    }
  } else {
    #pragma unroll
    for (int u = 0; u < 16; ++u) {
      int j = 16 * r + u - 1024;
      j = j < 0 ? -j : j;
      j = j >= L_ ? 2 * L_ - 2 - j : j;
      short b = f2bf(src[j]);
      if (u & 1) o[u >> 1] = b; else e[u >> 1] = b;
    }
  }
  *(short8*)&pl0[(size_t)bc * PL + p0] = e;
  *(short8*)&pl1[(size_t)bc * PL + p0] = o;
}

// ---------------- prep 2: windowed DFT-1024 weights, interleaved re/im rows ----------------
__global__ void prep_wb(short* __restrict__ wb0, short* __restrict__ wb1) {
  int id = blockIdx.x * 256 + threadIdx.x;          // < 2*1024*128 = 262144
  int s   = id >> 17;
  int row = (id >> 7) & 1023;
  int n8  = (id & 127) * 8;
  int kp  = row >> 1, e = row & 1;
  short8 ov;
  #pragma unroll
  for (int u = 0; u < 8; ++u) {
    int n1 = n8 + u;
    float win = 0.5f - 0.5f * cosf((float)(2 * n1 + s) * 3.0679615757712823e-3f);
    float tw;
    if (e == 0)       tw = cosf((float)((n1 * kp) & 1023) * 6.1359231515425649e-3f);
    else if (kp == 0) tw = (n1 & 1) ? -1.0f : 1.0f;       // re[512] row
    else              tw = -sinf((float)((n1 * kp) & 1023) * 6.1359231515425649e-3f);
    ov[u] = f2bf(win * tw);
  }
  short* wb = s ? wb1 : wb0;
  *(short8*)&wb[(size_t)row * KD + n8] = ov;
}

// ---------------- GEMM: 256m x (128col x 2pl), phase-pipelined, 3-slot ----------------
#define GLOAD16(g, l) __builtin_amdgcn_global_load_lds(                        \
    (const __attribute__((address_space(1))) void*)(g),                        \
    (__attribute__((address_space(3))) void*)(l), 16, 0, 0)

__global__ __launch_bounds__(512, 2) void stft_gemm(const short* __restrict__ pl0,
                                                    const short* __restrict__ pl1,
                                                    const short* __restrict__ wb0,
                                                    const short* __restrict__ wb1,
                                                    float* __restrict__ out) {
  // 3 slots x (A0[256][32] A1[256][32] B0[128][32] B1[128][32]) = 3 x 48KB
  // epilogue reuse: re[256][65] + im[256][65] fp32 = 133120 B
  __shared__ __align__(16) char lds[3 * SLOT];
  const int tid  = threadIdx.x;
  const int lane = tid & 63;
  const int wid  = tid >> 6;          // 0..7

  // ---- XCD map: all 8 nt of an mt share id%8 -> one XCD (bijective, m?) ----
  const int id = blockIdx.x;                   // 0..639
  const int mt = (id & 7) * 10 + (id >> 6);    // 0..79 (79 partially/fully dead)
  const int nt = (id >> 3) & 7;
  const int M0 = mt * 256;
  const int wm = wid >> 2, wn = wid & 3;       // 2m x 4n; wave: 128m x 32col x 2pl

  // ---- staging: 6 gload16/thread/K-tile (A:2pl x 2half, B:2pl) ----
  const int srow  = tid >> 2;                               // 0..127
  const int chunk = ((tid & 3) ^ ((tid >> 3) & 3)) * 8;     // inverse-swizzled src
  const short* aS[2][2];
  const short* bS[2];
  #pragma unroll
  for (int h = 0; h < 2; ++h) {
    int m = M0 + h * 128 + srow; if (m > M_ - 1) m = M_ - 1;   // clamp (not stored)
    int bc = m / T_;
    int t  = m - bc * T_;
    size_t base = (size_t)bc * PL + (size_t)t * 256 + chunk;
    aS[0][h] = pl0 + base;
    aS[1][h] = pl1 + base;
  }
  {
    int n = nt * 128 + srow;                                   // 0..1023
    size_t bb = (size_t)n * KD + chunk;
    bS[0] = wb0 + bb;
    bS[1] = wb1 + bb;
  }
  const int dst = tid * 16;

  // ---- fragment read offsets (proven conflict-free 64B-row XOR pattern) ----
  const int fr = lane & 15, kh = lane >> 4;
  const int xorb = (kh * 16) ^ ((fr & 6) << 3);
  int aOff[2][8], bOff[2][2];
  #pragma unroll
  for (int p = 0; p < 2; ++p) {
    #pragma unroll
    for (int i = 0; i < 8; ++i)
      aOff[p][i] = p * 16384 + (wm * 128 + i * 16 + fr) * 64 + xorb;
    #pragma unroll
    for (int j = 0; j < 2; ++j)
      bOff[p][j] = 32768 + p * 8192 + (wn * 32 + j * 16 + fr) * 64 + xorb;
  }

  f32x4 acc0[8][2], acc1[8][2];
  #pragma unroll
  for (int i = 0; i < 8; ++i)
    #pragma unroll
    for (int j = 0; j < 2; ++j) {
      acc0[i][j] = (f32x4){0.f, 0.f, 0.f, 0.f};
      acc1[i][j] = (f32x4){0.f, 0.f, 0.f, 0.f};
    }

  #define STAGE(S, KO) do { char* s_ = (S); const int ko_ = (KO);              \
      GLOAD16(aS[0][0] + ko_, s_ + dst);                                       \
      GLOAD16(aS[0][1] + ko_, s_ + 8192  + dst);                               \
      GLOAD16(aS[1][0] + ko_, s_ + 16384 + dst);                               \
      GLOAD16(aS[1][1] + ko_, s_ + 24576 + dst);                               \
      GLOAD16(bS[0]    + ko_, s_ + 32768 + dst);                               \
      GLOAD16(bS[1]    + ko_, s_ + 40960 + dst); } while (0)

  // ---- prologue: stage kt=0,1; wait kt=0; preload plane0 frags of kt=0 ----
  STAGE(lds, 0);
  STAGE(lds + SLOT, 32);
  asm volatile("s_waitcnt vmcnt(6)" ::: "memory");
  __builtin_amdgcn_s_barrier();

  short8 af0[8], af1[8], bf0[2], bf1[2];
  #pragma unroll
  for (int i = 0; i < 8; ++i) af0[i] = *(const short8*)(lds + aOff[0][i]);
  #pragma unroll
  for (int j = 0; j < 2; ++j) bf0[j] = *(const short8*)(lds + bOff[0][j]);

  // ---- main loop: 2 phases/K-tile; 1 barrier + 1 counted vmcnt per K-tile ----
  for (int kt = 0; kt < NKT; ++kt) {
    char* sR = lds + (kt % 3) * SLOT;

    // phase A: MFMA plane0(kt); issue DMA(kt+2); read plane1(kt) frags
    if (kt + 2 < NKT) STAGE(lds + ((kt + 2) % 3) * SLOT, (kt + 2) * 32);
    #pragma unroll
    for (int i = 0; i < 8; ++i) af1[i] = *(const short8*)(sR + aOff[1][i]);
    #pragma unroll
    for (int j = 0; j < 2; ++j) bf1[j] = *(const short8*)(sR + bOff[1][j]);
    __builtin_amdgcn_s_setprio(1);
    #pragma unroll
    for (int i = 0; i < 8; ++i)
      #pragma unroll
      for (int j = 0; j < 2; ++j)
        acc0[i][j] = __builtin_amdgcn_mfma_f32_16x16x32_bf16(af0[i], bf0[j],
                                                             acc0[i][j], 0, 0, 0);
    __builtin_amdgcn_s_setprio(0);

    // phase B: wait kt+1 DMA (counted); barrier; read plane0(kt+1); MFMA plane1(kt)
    if (kt + 2 < NKT)      asm volatile("s_waitcnt vmcnt(6)" ::: "memory");
    else if (kt + 1 < NKT) asm volatile("s_waitcnt vmcnt(0)" ::: "memory");
    asm volatile("s_waitcnt lgkmcnt(0)" ::: "memory");   // WAR guard (reads are old)
    __builtin_amdgcn_s_barrier();
    if (kt + 1 < NKT) {
      char* sN = lds + ((kt + 1) % 3) * SLOT;
      #pragma unroll
      for (int i = 0; i < 8; ++i) af0[i] = *(const short8*)(sN + aOff[0][i]);
      #pragma unroll
      for (int j = 0; j < 2; ++j) bf0[j] = *(const short8*)(sN + bOff[0][j]);
    }
    __builtin_amdgcn_s_setprio(1);
    #pragma unroll
    for (int i = 0; i < 8; ++i)
      #pragma unroll
      for (int j = 0; j < 2; ++j)
        acc1[i][j] = __builtin_amdgcn_mfma_f32_16x16x32_bf16(af1[i], bf1[j],
                                                             acc1[i][j], 0, 0, 0);
    __builtin_amdgcn_s_setprio(0);
  }

  // ---- epilogue: in-register twiddle (both planes in-wave), LDS-staged writes ----
  float* Lf = (float*)lds;
  float* outI = out + OUT_HALF;
  const float PIQ = 3.0679615757712823e-3f;     // pi/1024

  __syncthreads();   // main-loop LDS fully consumed before reuse

  #pragma unroll
  for (int pass = 0; pass < 2; ++pass) {
    #pragma unroll
    for (int j = 0; j < 2; ++j) {
      int c  = wn * 32 + j * 16 + fr;           // per-plane col 0..127
      int q  = c >> 1;                          // local 0..63
      float ang = (float)(nt * 64 + q) * PIQ;
      float tr = cosf(ang), sn = sinf(ang);
      bool odd  = c & 1;
      bool spec = (nt == 0) && (c == 1);        // Y[512] special slot
      float sgn = odd ? -sn : sn;
      int fidx = (odd ? IMBASE : 0) + (pass ? (63 - q) : q);
      #pragma unroll
      for (int i = 0; i < 8; ++i) {
        int grow = wm * 128 + i * 16 + kh * 4;
        #pragma unroll
        for (int r = 0; r < 4; ++r) {
          float v0 = acc0[i][j][r];
          float v1 = acc1[i][j][r];
          float p1 = __shfl_xor(v1, 1);
          float u  = tr * v1 + sgn * p1;
          float val = (pass == 0) ? (v0 + u) : (odd ? -(v0 - u) : (v0 - u));
          if (spec) val = 0.f;
          Lf[fidx + (grow + r) * 65] = val;
          if (spec && pass == 0) {
            int gm = M0 + grow + r;
            if (gm < M_) {                       // X[512] = Y0[512] - i*Y1[512]
              out [(size_t)gm * KCH + 512] = v0;
              outI[(size_t)gm * KCH + 512] = -v1;
            }
          }
        }
      }
    }
    __syncthreads();
    // coalesced write: 256 rows x 64 consecutive floats per array
    {
      int col0 = pass ? (1024 - nt * 64 - 63) : (nt * 64);
      #pragma unroll
      for (int i2 = 0; i2 < 32; ++i2) {
        int row = wid + i2 * 8;
        int gm  = M0 + row;
        if (gm < M_) {
          size_t rb = (size_t)gm * KCH + col0 + lane;
          out [rb] = Lf[row * 65 + lane];
          outI[rb] = Lf[IMBASE + row * 65 + lane];
        }
      }
    }
    __syncthreads();
  }
}

// ---------------- launcher ----------------
extern "C" void kernel_launch(void* const* d_in, const int* in_sizes, int n_in,
                              void* d_out, int out_size, void* d_ws, size_t ws_size,
                              hipStream_t stream) {
  const float* x = (const float*)d_in[0];
  float* out = (float*)d_out;

  short* pl0 = (short*)d_ws;                        // 64*81024 bf16
  short* pl1 = pl0 + (size_t)BC * PL;
  short* wb0 = pl1 + (size_t)BC * PL;               // 1024*1024
  short* wb1 = wb0 + (size_t)1024 * KD;             // total 24.9 MB

  prep_planes<<<2532, 256, 0, stream>>>(x, pl0, pl1);
  prep_wb<<<1024, 256, 0, stream>>>(wb0, wb1);

  stft_gemm<<<NWG, 512, 0, stream>>>(pl0, pl1, wb0, wb1, out);
}

// Round 12
// 137.676 us; speedup vs baseline: 2.3252x; 1.0974x over previous
//
#include <hip/hip_runtime.h>

// ---------------- problem constants ----------------
#define B_     32
#define C_     2
#define L_     160000
#define HOP    512
#define PAD    1024
#define LPAD   162048            // L_ + 2*PAD
#define T_     313               // frames
#define BC     64                // B_*C_
#define M_     20032             // BC*T_
#define KCH    1025              // output channels per (real|imag)
#define OUT_HALF 20532800UL      // M_*KCH
#define PL     81024             // plane length per bc (LPAD/2)
#define KD     1024              // decimated K
#define NKT    32                // KD/32 K-tiles
#define MTP    160               // M tiles padded to 8*20 (157 real)
#define NWG    1280              // MTP*8
#define ZSTR   132               // epilogue zone row stride (words): 528B, 8B-aligned
#define Z1     8448              // zone-1 word offset: 64*132

typedef __attribute__((ext_vector_type(8))) short short8;
typedef __attribute__((ext_vector_type(4))) float f32x4;

static __device__ __forceinline__ short f2bf(float f) {
  union { float f; unsigned u; } v; v.f = f;
  unsigned u = v.u;
  unsigned r = (u + 0x7fffu + ((u >> 16) & 1u)) >> 16;  // RNE
  return (short)r;
}

// ---------------- prep 1: even/odd deinterleaved reflect-padded planes ----------------
__global__ void prep_planes(const float* __restrict__ x,
                            short* __restrict__ pl0, short* __restrict__ pl1) {
  int v = blockIdx.x * 256 + threadIdx.x;           // < 64*10128 = 648192
  int bc = v / 10128;
  int r  = v - bc * 10128;
  int p0 = r * 8;                                   // 8 p-positions -> 16 samples
  const float* src = x + (size_t)bc * L_;
  short8 e, o;
  if (r >= 64 && r <= 10000) {                      // fully interior
    int j0 = 16 * r - 1024;
    #pragma unroll
    for (int qq = 0; qq < 4; ++qq) {
      float4 f = *(const float4*)(src + j0 + qq * 4);
      e[qq * 2 + 0] = f2bf(f.x); o[qq * 2 + 0] = f2bf(f.y);
      e[qq * 2 + 1] = f2bf(f.z); o[qq * 2 + 1] = f2bf(f.w);
    }
  } else {
    #pragma unroll
    for (int u = 0; u < 16; ++u) {
      int j = 16 * r + u - 1024;
      j = j < 0 ? -j : j;
      j = j >= L_ ? 2 * L_ - 2 - j : j;
      short b = f2bf(src[j]);
      if (u & 1) o[u >> 1] = b; else e[u >> 1] = b;
    }
  }
  *(short8*)&pl0[(size_t)bc * PL + p0] = e;
  *(short8*)&pl1[(size_t)bc * PL + p0] = o;
}

// ---------------- prep 2: windowed DFT-1024 weights, interleaved re/im rows ----------------
__global__ void prep_wb(short* __restrict__ wb0, short* __restrict__ wb1) {
  int id = blockIdx.x * 256 + threadIdx.x;          // < 2*1024*128 = 262144
  int s   = id >> 17;
  int row = (id >> 7) & 1023;
  int n8  = (id & 127) * 8;
  int kp  = row >> 1, e = row & 1;
  short8 ov;
  #pragma unroll
  for (int u = 0; u < 8; ++u) {
    int n1 = n8 + u;
    float win = 0.5f - 0.5f * cosf((float)(2 * n1 + s) * 3.0679615757712823e-3f); // pi/1024
    float tw;
    if (e == 0)       tw = cosf((float)((n1 * kp) & 1023) * 6.1359231515425649e-3f); // 2pi/1024
    else if (kp == 0) tw = (n1 & 1) ? -1.0f : 1.0f;       // cos(pi*n1): re[512] row
    else              tw = -sinf((float)((n1 * kp) & 1023) * 6.1359231515425649e-3f);
    ov[u] = f2bf(win * tw);
  }
  short* wb = s ? wb1 : wb0;
  *(short8*)&wb[(size_t)row * KD + n8] = ov;
}

// ---------------- GEMM: 128x128 tile, 512 thr, dual-plane acc, BK=32 (r7 loop) ----------------
#define GLOAD16(g, l) __builtin_amdgcn_global_load_lds(                        \
    (const __attribute__((address_space(1))) void*)(g),                        \
    (__attribute__((address_space(3))) void*)(l), 16, 0, 0)

__global__ __launch_bounds__(512, 4) void stft_gemm(const short* __restrict__ pl0,
                                                    const short* __restrict__ pl1,
                                                    const short* __restrict__ wb0,
                                                    const short* __restrict__ wb1,
                                                    float* __restrict__ out) {
  // main loop: 2 buffers x (A0,A1,B0,B1 each [128][32] = 8KB) = 64KB
  // epilogue reuse: raw zones [2 planes][64 rows][132] fp32 = 67584 B
  __shared__ __align__(16) char lds[67584];
  const int tid  = threadIdx.x;
  const int lane = tid & 63;
  const int wid  = tid >> 6;          // 0..7

  // ---- XCD remap: 8 nt-blocks sharing an A-panel are consecutive ids with the
  // same id%8 -> same XCD -> A fetched ~once per panel; B (4MB) L2-resident.
  const int id = blockIdx.x;                   // 0..1279
  const int mt = (id & 7) * 20 + (id >> 6);    // 0..159 (>=157 dead-padded)
  const int nt = (id >> 3) & 7;
  const int M0 = mt * 128, N0 = nt * 128;

  // ---- staging: 1 instr per operand per plane; 512 threads cover [128][32] ----
  const int srow = tid >> 2;                                 // 0..127
  const int chunkSwz = ((tid & 3) ^ ((tid >> 3) & 3)) * 8;   // inverse-swizzled src
  const short* aP[2];
  const short* bP[2];
  {
    int m = M0 + srow; if (m > M_ - 1) m = M_ - 1;           // clamp (not stored)
    int bc = m / T_;
    int t  = m - bc * T_;
    size_t base = (size_t)bc * PL + (size_t)t * 256 + chunkSwz;
    aP[0] = pl0 + base;
    aP[1] = pl1 + base;
    size_t bb = (size_t)(N0 + srow) * KD + chunkSwz;
    bP[0] = wb0 + bb;
    bP[1] = wb1 + bb;
  }
  const int dstOff = tid * 16;   // linear LDS dest (waveBase + lane*16 invariant)

  // ---- fragment read offsets (proven conflict-free 64B-row XOR pattern) ----
  const int wr = wid >> 2, wc = wid & 3;    // 2m x 4n waves; per-wave 64x32
  const int fr = lane & 15;
  const int xorb = ((lane >> 4) * 16) ^ ((fr & 6) << 3);
  int afOff[2][4], bfOff[2][2];
  #pragma unroll
  for (int s = 0; s < 2; ++s) {
    #pragma unroll
    for (int i = 0; i < 4; ++i)
      afOff[s][i] = s * 8192 + (wr * 64 + i * 16 + fr) * 64 + xorb;
    #pragma unroll
    for (int j = 0; j < 2; ++j)
      bfOff[s][j] = 16384 + s * 8192 + (wc * 32 + j * 16 + fr) * 64 + xorb;
  }

  f32x4 acc[2][4][2];
  #pragma unroll
  for (int s = 0; s < 2; ++s)
    #pragma unroll
    for (int i = 0; i < 4; ++i)
      #pragma unroll
      for (int j = 0; j < 2; ++j) acc[s][i][j] = (f32x4){0.f, 0.f, 0.f, 0.f};

  // ---- prologue: stage kt=0, s0 group then s1 group (2 loads each) ----
  GLOAD16(aP[0], lds + dstOff);
  GLOAD16(bP[0], lds + 16384 + dstOff);
  GLOAD16(aP[1], lds + 8192 + dstOff);
  GLOAD16(bP[1], lds + 24576 + dstOff);

  // ---- main loop: 2 phases (s=0,1) per K-tile; counted vmcnt(2) [r7, proven] ----
  for (int kt = 0; kt < NKT; ++kt) {
    char* bufR = lds + (kt & 1) * 32768;
    char* bufW = lds + ((kt + 1) & 1) * 32768;
    const int kos = (kt + 1) * 32;
    const bool st = (kt < NKT - 1);

    // phase s=0
    asm volatile("s_waitcnt vmcnt(2)" ::: "memory");   // s0(kt) landed
    __builtin_amdgcn_s_barrier();
    if (st) {
      GLOAD16(aP[0] + kos, bufW + dstOff);
      GLOAD16(bP[0] + kos, bufW + 16384 + dstOff);
    }
    short8 af0[4], bf0[2];
    #pragma unroll
    for (int i = 0; i < 4; ++i) af0[i] = *(const short8*)(bufR + afOff[0][i]);
    #pragma unroll
    for (int j = 0; j < 2; ++j) bf0[j] = *(const short8*)(bufR + bfOff[0][j]);
    __builtin_amdgcn_s_barrier();
    __builtin_amdgcn_s_setprio(1);
    #pragma unroll
    for (int i = 0; i < 4; ++i)
      #pragma unroll
      for (int j = 0; j < 2; ++j)
        acc[0][i][j] = __builtin_amdgcn_mfma_f32_16x16x32_bf16(af0[i], bf0[j],
                                                               acc[0][i][j], 0, 0, 0);
    __builtin_amdgcn_s_setprio(0);

    // phase s=1
    if (st) asm volatile("s_waitcnt vmcnt(2)" ::: "memory");  // s1(kt) landed
    else    asm volatile("s_waitcnt vmcnt(0)" ::: "memory");
    __builtin_amdgcn_s_barrier();
    if (st) {
      GLOAD16(aP[1] + kos, bufW + 8192 + dstOff);
      GLOAD16(bP[1] + kos, bufW + 24576 + dstOff);
    }
    short8 af1[4], bf1[2];
    #pragma unroll
    for (int i = 0; i < 4; ++i) af1[i] = *(const short8*)(bufR + afOff[1][i]);
    #pragma unroll
    for (int j = 0; j < 2; ++j) bf1[j] = *(const short8*)(bufR + bfOff[1][j]);
    __builtin_amdgcn_s_barrier();
    __builtin_amdgcn_s_setprio(1);
    #pragma unroll
    for (int i = 0; i < 4; ++i)
      #pragma unroll
      for (int j = 0; j < 2; ++j)
        acc[1][i][j] = __builtin_amdgcn_mfma_f32_16x16x32_bf16(af1[i], bf1[j],
                                                               acc[1][i][j], 0, 0, 0);
    __builtin_amdgcn_s_setprio(0);
  }

  // ---- epilogue v3: raw-stage once, single combine pass per row-half ----
  // zone layout: Lf[pl*Z1 + row*ZSTR + col], col in [0,128): even=re, odd=im.
  // stage writes: 2-way bank alias (free); combine reads: contiguous b64 (free).
  float* Lf = (float*)lds;
  float* outI = out + OUT_HALF;
  const int q = lane;                               // 0..63 (local q index)
  const float ang = (float)(nt * 64 + q) * 3.0679615757712823e-3f;   // pi*k/1024
  const float tr = cosf(ang), sn = sinf(ang);       // t = tr - i*sn
  const int rgrp = (lane >> 4) << 2;

  __syncthreads();   // all main-loop LDS reads complete before reuse

  #pragma unroll
  for (int h = 0; h < 2; ++h) {
    if (wr == h) {   // owner waves stage raw acc for rows [h*64, h*64+64)
      #pragma unroll
      for (int pl = 0; pl < 2; ++pl)
        #pragma unroll
        for (int i = 0; i < 4; ++i)
          #pragma unroll
          for (int j = 0; j < 2; ++j)
            #pragma unroll
            for (int r = 0; r < 4; ++r)
              Lf[pl * Z1 + (i * 16 + rgrp + r) * ZSTR + wc * 32 + j * 16 + fr]
                 = acc[pl][i][j][r];
    }
    __syncthreads();
    // combine + store: lane = q, 8 rows per iteration across the 8 waves
    #pragma unroll
    for (int it = 0; it < 8; ++it) {
      int row = wid + it * 8;                       // 0..63
      int gm  = M0 + h * 64 + row;
      if (gm < M_) {
        float2 y0 = *(const float2*)&Lf[row * ZSTR + 2 * q];
        float2 y1 = *(const float2*)&Lf[Z1 + row * ZSTR + 2 * q];
        float ur = tr * y1.x + sn * y1.y;           // Re(t*Y1)
        float ui = tr * y1.y - sn * y1.x;           // Im(t*Y1)
        size_t rb = (size_t)gm * KCH;
        if (nt == 0 && q == 0) {
          // cols 0,1 are the special real rows: Y[0] and Y[512]
          out [rb + 0]    = y0.x + y1.x;            // X[0] = Y0[0]+Y1[0]
          outI[rb + 0]    = 0.f;
          out [rb + 1024] = y0.x - y1.x;            // X[1024] = Y0[0]-Y1[0]
          outI[rb + 1024] = 0.f;
          out [rb + 512]  = y0.y;                   // X[512] = Y0[512] - i*Y1[512]
          outI[rb + 512]  = -y1.y;
        } else {
          int kq = nt * 64 + q;
          out [rb + kq]        = y0.x + ur;         // X[k]
          outI[rb + kq]        = y0.y + ui;
          out [rb + 1024 - kq] = y0.x - ur;         // X[1024-k] (conj pair)
          outI[rb + 1024 - kq] = -(y0.y - ui);
        }
      }
    }
    __syncthreads();   // zones reused by next row-half
  }
}

// ---------------- launcher ----------------
extern "C" void kernel_launch(void* const* d_in, const int* in_sizes, int n_in,
                              void* d_out, int out_size, void* d_ws, size_t ws_size,
                              hipStream_t stream) {
  const float* x = (const float*)d_in[0];
  float* out = (float*)d_out;

  short* pl0 = (short*)d_ws;                        // 64*81024 bf16
  short* pl1 = pl0 + (size_t)BC * PL;
  short* wb0 = pl1 + (size_t)BC * PL;               // 1024*1024
  short* wb1 = wb0 + (size_t)1024 * KD;             // total 24.9 MB

  prep_planes<<<2532, 256, 0, stream>>>(x, pl0, pl1);
  prep_wb<<<1024, 256, 0, stream>>>(wb0, wb1);

  stft_gemm<<<NWG, 512, 0, stream>>>(pl0, pl1, wb0, wb1, out);
}

// Round 14
// 137.025 us; speedup vs baseline: 2.3362x; 1.0047x over previous
//
#include <hip/hip_runtime.h>

// ---------------- problem constants ----------------
#define B_     32
#define C_     2
#define L_     160000
#define HOP    512
#define PAD    1024
#define LPAD   162048            // L_ + 2*PAD
#define T_     313               // frames
#define BC     64                // B_*C_
#define M_     20032             // BC*T_
#define KCH    1025              // output channels per (real|imag)
#define OUT_HALF 20532800UL      // M_*KCH
#define PL     81024             // plane length per bc (LPAD/2)
#define KD     1024              // decimated K
#define NKT    32                // KD/32 K-tiles
#define MTP    160               // M tiles padded to 8*20 (157 real)
#define NWG    1280              // MTP*8
#define ZSTR   132               // epilogue zone row stride (words): 528B
#define Z1     8448              // zone-1 word offset: 64*132

typedef __attribute__((ext_vector_type(8))) short short8;
typedef __attribute__((ext_vector_type(4))) float f32x4;

static __device__ __forceinline__ short f2bf(float f) {
  union { float f; unsigned u; } v; v.f = f;
  unsigned u = v.u;
  unsigned r = (u + 0x7fffu + ((u >> 16) & 1u)) >> 16;  // RNE
  return (short)r;
}

// ---------------- prep 1: even/odd deinterleaved reflect-padded planes ----------------
__global__ void prep_planes(const float* __restrict__ x,
                            short* __restrict__ pl0, short* __restrict__ pl1) {
  int v = blockIdx.x * 256 + threadIdx.x;           // < 64*10128 = 648192
  int bc = v / 10128;
  int r  = v - bc * 10128;
  int p0 = r * 8;                                   // 8 p-positions -> 16 samples
  const float* src = x + (size_t)bc * L_;
  short8 e, o;
  if (r >= 64 && r <= 10000) {                      // fully interior
    int j0 = 16 * r - 1024;
    #pragma unroll
    for (int qq = 0; qq < 4; ++qq) {
      float4 f = *(const float4*)(src + j0 + qq * 4);
      e[qq * 2 + 0] = f2bf(f.x); o[qq * 2 + 0] = f2bf(f.y);
      e[qq * 2 + 1] = f2bf(f.z); o[qq * 2 + 1] = f2bf(f.w);
    }
  } else {
    #pragma unroll
    for (int u = 0; u < 16; ++u) {
      int j = 16 * r + u - 1024;
      j = j < 0 ? -j : j;
      j = j >= L_ ? 2 * L_ - 2 - j : j;
      short b = f2bf(src[j]);
      if (u & 1) o[u >> 1] = b; else e[u >> 1] = b;
    }
  }
  *(short8*)&pl0[(size_t)bc * PL + p0] = e;
  *(short8*)&pl1[(size_t)bc * PL + p0] = o;
}

// ---------------- prep 2: windowed DFT-1024 weights, interleaved re/im rows ----------------
__global__ void prep_wb(short* __restrict__ wb0, short* __restrict__ wb1) {
  int id = blockIdx.x * 256 + threadIdx.x;          // < 2*1024*128 = 262144
  int s   = id >> 17;
  int row = (id >> 7) & 1023;
  int n8  = (id & 127) * 8;
  int kp  = row >> 1, e = row & 1;
  short8 ov;
  #pragma unroll
  for (int u = 0; u < 8; ++u) {
    int n1 = n8 + u;
    float win = 0.5f - 0.5f * cosf((float)(2 * n1 + s) * 3.0679615757712823e-3f); // pi/1024
    float tw;
    if (e == 0)       tw = cosf((float)((n1 * kp) & 1023) * 6.1359231515425649e-3f); // 2pi/1024
    else if (kp == 0) tw = (n1 & 1) ? -1.0f : 1.0f;       // cos(pi*n1): re[512] row
    else              tw = -sinf((float)((n1 * kp) & 1023) * 6.1359231515425649e-3f);
    ov[u] = f2bf(win * tw);
  }
  short* wb = s ? wb1 : wb0;
  *(short8*)&wb[(size_t)row * KD + n8] = ov;
}

// ---------------- GEMM: 128x128 tile, 512 thr, dual-plane acc, BK=32 ----------------
#define GLOAD16(g, l) __builtin_amdgcn_global_load_lds(                        \
    (const __attribute__((address_space(1))) void*)(g),                        \
    (__attribute__((address_space(3))) void*)(l), 16, 0, 0)

__global__ __launch_bounds__(512, 4) void stft_gemm(const short* __restrict__ pl0,
                                                    const short* __restrict__ pl1,
                                                    const short* __restrict__ wb0,
                                                    const short* __restrict__ wb1,
                                                    float* __restrict__ out) {
  // main loop: 2 buffers x (A0,A1,B0,B1 each [128][32] = 8KB) = 64KB
  // epilogue reuse: raw zones [2 planes][64 rows][132] fp32 = 67584 B
  __shared__ __align__(16) char lds[67584];
  const int tid  = threadIdx.x;
  const int lane = tid & 63;
  const int wid  = tid >> 6;          // 0..7

  // ---- XCD remap: 8 nt-blocks sharing an A-panel are consecutive ids with the
  // same id%8 -> same XCD -> A fetched ~once per panel; B (4MB) L2-resident.
  const int id = blockIdx.x;                   // 0..1279
  const int mt = (id & 7) * 20 + (id >> 6);    // 0..159 (>=157 dead-padded)
  const int nt = (id >> 3) & 7;
  const int M0 = mt * 128, N0 = nt * 128;

  // ---- staging: 1 instr per operand per plane; 512 threads cover [128][32] ----
  const int srow = tid >> 2;                                 // 0..127
  const int chunkSwz = ((tid & 3) ^ ((tid >> 3) & 3)) * 8;   // inverse-swizzled src
  const short* aP[2];
  const short* bP[2];
  {
    int m = M0 + srow; if (m > M_ - 1) m = M_ - 1;           // clamp (not stored)
    int bc = m / T_;
    int t  = m - bc * T_;
    size_t base = (size_t)bc * PL + (size_t)t * 256 + chunkSwz;
    aP[0] = pl0 + base;
    aP[1] = pl1 + base;
    size_t bb = (size_t)(N0 + srow) * KD + chunkSwz;
    bP[0] = wb0 + bb;
    bP[1] = wb1 + bb;
  }
  const int dstOff = tid * 16;   // linear LDS dest (waveBase + lane*16 invariant)

  // ---- fragment read offsets (proven conflict-free 64B-row XOR pattern) ----
  const int wr = wid >> 2, wc = wid & 3;    // 2m x 4n waves; per-wave 64x32
  const int fr = lane & 15;
  const int xorb = ((lane >> 4) * 16) ^ ((fr & 6) << 3);
  int afOff[2][4], bfOff[2][2];
  #pragma unroll
  for (int s = 0; s < 2; ++s) {
    #pragma unroll
    for (int i = 0; i < 4; ++i)
      afOff[s][i] = s * 8192 + (wr * 64 + i * 16 + fr) * 64 + xorb;
    #pragma unroll
    for (int j = 0; j < 2; ++j)
      bfOff[s][j] = 16384 + s * 8192 + (wc * 32 + j * 16 + fr) * 64 + xorb;
  }

  f32x4 acc[2][4][2];
  #pragma unroll
  for (int s = 0; s < 2; ++s)
    #pragma unroll
    for (int i = 0; i < 4; ++i)
      #pragma unroll
      for (int j = 0; j < 2; ++j) acc[s][i][j] = (f32x4){0.f, 0.f, 0.f, 0.f};

  // ---- prologue: stage kt=0, s0 group then s1 group (2 loads each) ----
  GLOAD16(aP[0], lds + dstOff);
  GLOAD16(bP[0], lds + 16384 + dstOff);
  GLOAD16(aP[1], lds + 8192 + dstOff);
  GLOAD16(bP[1], lds + 24576 + dstOff);

  // ---- main loop: 2 phases/K-tile; ONE {vmcnt; barrier} per phase ----
  // WAR safety without mid-phase barriers: a wave's ds_reads of buf(kt) drain
  // (compiler lgkmcnt) before its last MFMA issues -> before it reaches the
  // next phase-top barrier; DMA writes into that buffer are issued only after
  // that barrier. The "memory"-clobbered vmcnt asm pins compiler ordering.
  for (int kt = 0; kt < NKT; ++kt) {
    char* bufR = lds + (kt & 1) * 32768;
    char* bufW = lds + ((kt + 1) & 1) * 32768;
    const int kos = (kt + 1) * 32;
    const bool st = (kt < NKT - 1);

    // phase s=0
    asm volatile("s_waitcnt vmcnt(2)" ::: "memory");   // s0(kt) landed
    __builtin_amdgcn_s_barrier();
    if (st) {
      GLOAD16(aP[0] + kos, bufW + dstOff);
      GLOAD16(bP[0] + kos, bufW + 16384 + dstOff);
    }
    short8 af0[4], bf0[2];
    #pragma unroll
    for (int i = 0; i < 4; ++i) af0[i] = *(const short8*)(bufR + afOff[0][i]);
    #pragma unroll
    for (int j = 0; j < 2; ++j) bf0[j] = *(const short8*)(bufR + bfOff[0][j]);
    __builtin_amdgcn_s_setprio(1);
    #pragma unroll
    for (int i = 0; i < 4; ++i)
      #pragma unroll
      for (int j = 0; j < 2; ++j)
        acc[0][i][j] = __builtin_amdgcn_mfma_f32_16x16x32_bf16(af0[i], bf0[j],
                                                               acc[0][i][j], 0, 0, 0);
    __builtin_amdgcn_s_setprio(0);

    // phase s=1
    if (st) asm volatile("s_waitcnt vmcnt(2)" ::: "memory");  // s1(kt) landed
    else    asm volatile("s_waitcnt vmcnt(0)" ::: "memory");
    __builtin_amdgcn_s_barrier();
    if (st) {
      GLOAD16(aP[1] + kos, bufW + 8192 + dstOff);
      GLOAD16(bP[1] + kos, bufW + 24576 + dstOff);
    }
    short8 af1[4], bf1[2];
    #pragma unroll
    for (int i = 0; i < 4; ++i) af1[i] = *(const short8*)(bufR + afOff[1][i]);
    #pragma unroll
    for (int j = 0; j < 2; ++j) bf1[j] = *(const short8*)(bufR + bfOff[1][j]);
    __builtin_amdgcn_s_setprio(1);
    #pragma unroll
    for (int i = 0; i < 4; ++i)
      #pragma unroll
      for (int j = 0; j < 2; ++j)
        acc[1][i][j] = __builtin_amdgcn_mfma_f32_16x16x32_bf16(af1[i], bf1[j],
                                                               acc[1][i][j], 0, 0, 0);
    __builtin_amdgcn_s_setprio(0);
  }

  // ---- epilogue v3 (r12-proven): raw-stage once per row-half, single combine ----
  // zone layout: Lf[pl*Z1 + row*ZSTR + col], col in [0,128): even=re, odd=im.
  float* Lf = (float*)lds;
  float* outI = out + OUT_HALF;
  const int q = lane;                               // 0..63 (local q index)
  const float ang = (float)(nt * 64 + q) * 3.0679615757712823e-3f;   // pi*k/1024
  const float tr = cosf(ang), sn = sinf(ang);       // t = tr - i*sn
  const int rgrp = (lane >> 4) << 2;

  __syncthreads();   // all main-loop LDS reads complete before reuse

  #pragma unroll
  for (int h = 0; h < 2; ++h) {
    if (wr == h) {   // owner waves stage raw acc for rows [h*64, h*64+64)
      #pragma unroll
      for (int pl = 0; pl < 2; ++pl)
        #pragma unroll
        for (int i = 0; i < 4; ++i)
          #pragma unroll
          for (int j = 0; j < 2; ++j)
            #pragma unroll
            for (int r = 0; r < 4; ++r)
              Lf[pl * Z1 + (i * 16 + rgrp + r) * ZSTR + wc * 32 + j * 16 + fr]
                 = acc[pl][i][j][r];
    }
    __syncthreads();
    // combine + store: lane = q, 8 rows per iteration across the 8 waves
    #pragma unroll
    for (int it = 0; it < 8; ++it) {
      int row = wid + it * 8;                       // 0..63
      int gm  = M0 + h * 64 + row;
      if (gm < M_) {
        float2 y0 = *(const float2*)&Lf[row * ZSTR + 2 * q];
        float2 y1 = *(const float2*)&Lf[Z1 + row * ZSTR + 2 * q];
        float ur = tr * y1.x + sn * y1.y;           // Re(t*Y1)
        float ui = tr * y1.y - sn * y1.x;           // Im(t*Y1)
        size_t rb = (size_t)gm * KCH;
        if (nt == 0 && q == 0) {
          // cols 0,1 are the special real rows: Y[0] and Y[512]
          out [rb + 0]    = y0.x + y1.x;            // X[0] = Y0[0]+Y1[0]
          outI[rb + 0]    = 0.f;
          out [rb + 1024] = y0.x - y1.x;            // X[1024] = Y0[0]-Y1[0]
          outI[rb + 1024] = 0.f;
          out [rb + 512]  = y0.y;                   // X[512] = Y0[512] - i*Y1[512]
          outI[rb + 512]  = -y1.y;
        } else {
          int kq = nt * 64 + q;
          out [rb + kq]        = y0.x + ur;         // X[k]
          outI[rb + kq]        = y0.y + ui;
          out [rb + 1024 - kq] = y0.x - ur;         // X[1024-k] (conj pair)
          outI[rb + 1024 - kq] = -(y0.y - ui);
        }
      }
    }
    __syncthreads();   // zones reused by next row-half
  }
}

// ---------------- launcher ----------------
extern "C" void kernel_launch(void* const* d_in, const int* in_sizes, int n_in,
                              void* d_out, int out_size, void* d_ws, size_t ws_size,
                              hipStream_t stream) {
  const float* x = (const float*)d_in[0];
  float* out = (float*)d_out;

  short* pl0 = (short*)d_ws;                        // 64*81024 bf16
  short* pl1 = pl0 + (size_t)BC * PL;
  short* wb0 = pl1 + (size_t)BC * PL;               // 1024*1024
  short* wb1 = wb0 + (size_t)1024 * KD;             // total 24.9 MB

  prep_planes<<<2532, 256, 0, stream>>>(x, pl0, pl1);
  prep_wb<<<1024, 256, 0, stream>>>(wb0, wb1);

  stft_gemm<<<NWG, 512, 0, stream>>>(pl0, pl1, wb0, wb1, out);
}

// Round 15
// 135.456 us; speedup vs baseline: 2.3633x; 1.0116x over previous
//
#include <hip/hip_runtime.h>

// ---------------- problem constants ----------------
#define B_     32
#define C_     2
#define L_     160000
#define HOP    512
#define PAD    1024
#define LPAD   162048            // L_ + 2*PAD
#define T_     313               // frames
#define BC     64                // B_*C_
#define M_     20032             // BC*T_
#define KCH    1025              // output channels per (real|imag)
#define OUT_HALF 20532800UL      // M_*KCH
#define PL     81024             // plane length per bc (LPAD/2)
#define KD     1024              // decimated K
#define NKT    32                // KD/32 K-tiles
#define NWG    1280              // 160*8 (24 dead blocks early-exit)
#define ZSTR   132               // epilogue zone row stride (words): 528B
#define Z1     8448              // zone-1 word offset: 64*132
#define PREP_PLANE_BLOCKS 2532   // prep grid split

typedef __attribute__((ext_vector_type(8))) short short8;
typedef __attribute__((ext_vector_type(4))) float f32x4;

static __device__ __forceinline__ short f2bf(float f) {
  union { float f; unsigned u; } v; v.f = f;
  unsigned u = v.u;
  unsigned r = (u + 0x7fffu + ((u >> 16) & 1u)) >> 16;  // RNE
  return (short)r;
}

// ---------------- fused prep: planes + weights in one launch ----------------
__global__ void prep_all(const float* __restrict__ x,
                         short* __restrict__ pl0, short* __restrict__ pl1,
                         short* __restrict__ wb0, short* __restrict__ wb1) {
  int b = blockIdx.x;
  if (b < PREP_PLANE_BLOCKS) {
    // ---- even/odd deinterleaved reflect-padded planes ----
    int v = b * 256 + threadIdx.x;                  // < 64*10128 = 648192
    int bc = v / 10128;
    int r  = v - bc * 10128;
    int p0 = r * 8;                                 // 8 p-positions -> 16 samples
    const float* src = x + (size_t)bc * L_;
    short8 e, o;
    if (r >= 64 && r <= 10000) {                    // fully interior
      int j0 = 16 * r - 1024;
      #pragma unroll
      for (int qq = 0; qq < 4; ++qq) {
        float4 f = *(const float4*)(src + j0 + qq * 4);
        e[qq * 2 + 0] = f2bf(f.x); o[qq * 2 + 0] = f2bf(f.y);
        e[qq * 2 + 1] = f2bf(f.z); o[qq * 2 + 1] = f2bf(f.w);
      }
    } else {
      #pragma unroll
      for (int u = 0; u < 16; ++u) {
        int j = 16 * r + u - 1024;
        j = j < 0 ? -j : j;
        j = j >= L_ ? 2 * L_ - 2 - j : j;
        short bb = f2bf(src[j]);
        if (u & 1) o[u >> 1] = bb; else e[u >> 1] = bb;
      }
    }
    *(short8*)&pl0[(size_t)bc * PL + p0] = e;
    *(short8*)&pl1[(size_t)bc * PL + p0] = o;
  } else {
    // ---- windowed DFT-1024 weights, interleaved re/im rows ----
    int id = (b - PREP_PLANE_BLOCKS) * 256 + threadIdx.x;  // < 262144
    int s   = id >> 17;
    int row = (id >> 7) & 1023;
    int n8  = (id & 127) * 8;
    int kp  = row >> 1, e = row & 1;
    short8 ov;
    #pragma unroll
    for (int u = 0; u < 8; ++u) {
      int n1 = n8 + u;
      float win = 0.5f - 0.5f * cosf((float)(2 * n1 + s) * 3.0679615757712823e-3f);
      float tw;
      if (e == 0)       tw = cosf((float)((n1 * kp) & 1023) * 6.1359231515425649e-3f);
      else if (kp == 0) tw = (n1 & 1) ? -1.0f : 1.0f;     // cos(pi*n1): re[512] row
      else              tw = -sinf((float)((n1 * kp) & 1023) * 6.1359231515425649e-3f);
      ov[u] = f2bf(win * tw);
    }
    short* wb = s ? wb1 : wb0;
    *(short8*)&wb[(size_t)row * KD + n8] = ov;
  }
}

// ---------------- GEMM: 128x128 tile, 512 thr, dual-plane acc, BK=32 ----------------
#define GLOAD16(g, l) __builtin_amdgcn_global_load_lds(                        \
    (const __attribute__((address_space(1))) void*)(g),                        \
    (__attribute__((address_space(3))) void*)(l), 16, 0, 0)

__global__ __launch_bounds__(512, 4) void stft_gemm(const short* __restrict__ pl0,
                                                    const short* __restrict__ pl1,
                                                    const short* __restrict__ wb0,
                                                    const short* __restrict__ wb1,
                                                    float* __restrict__ out) {
  // main loop: 2 buffers x (A0,A1,B0,B1 each [128][32] = 8KB) = 64KB
  // epilogue reuse: raw zones [2 planes][64 rows][132] fp32 = 67584 B
  __shared__ __align__(16) char lds[67584];
  const int tid  = threadIdx.x;
  const int lane = tid & 63;
  const int wid  = tid >> 6;          // 0..7

  // ---- XCD remap: 8 nt-blocks sharing an A-panel are consecutive ids with the
  // same id%8 -> same XCD -> A fetched ~once per panel; B (4MB) L2-resident.
  const int id = blockIdx.x;                   // 0..1279
  const int mt = (id & 7) * 20 + (id >> 6);    // 0..159
  if (mt >= 157) return;                       // dead-padded blocks: exit early
  const int nt = (id >> 3) & 7;
  const int M0 = mt * 128, N0 = nt * 128;

  // ---- staging: 1 instr per operand per plane; 512 threads cover [128][32] ----
  const int srow = tid >> 2;                                 // 0..127
  const int chunkSwz = ((tid & 3) ^ ((tid >> 3) & 3)) * 8;   // inverse-swizzled src
  const short* aP[2];
  const short* bP[2];
  {
    int m = M0 + srow; if (m > M_ - 1) m = M_ - 1;           // clamp (not stored)
    int bc = m / T_;
    int t  = m - bc * T_;
    size_t base = (size_t)bc * PL + (size_t)t * 256 + chunkSwz;
    aP[0] = pl0 + base;
    aP[1] = pl1 + base;
    size_t bb = (size_t)(N0 + srow) * KD + chunkSwz;
    bP[0] = wb0 + bb;
    bP[1] = wb1 + bb;
  }
  const int dstOff = tid * 16;   // linear LDS dest (waveBase + lane*16 invariant)

  // ---- fragment read offsets (proven conflict-free 64B-row XOR pattern) ----
  const int wr = wid >> 2, wc = wid & 3;    // 2m x 4n waves; per-wave 64x32
  const int fr = lane & 15;
  const int xorb = ((lane >> 4) * 16) ^ ((fr & 6) << 3);
  int afOff[2][4], bfOff[2][2];
  #pragma unroll
  for (int s = 0; s < 2; ++s) {
    #pragma unroll
    for (int i = 0; i < 4; ++i)
      afOff[s][i] = s * 8192 + (wr * 64 + i * 16 + fr) * 64 + xorb;
    #pragma unroll
    for (int j = 0; j < 2; ++j)
      bfOff[s][j] = 16384 + s * 8192 + (wc * 32 + j * 16 + fr) * 64 + xorb;
  }

  f32x4 acc[2][4][2];
  #pragma unroll
  for (int s = 0; s < 2; ++s)
    #pragma unroll
    for (int i = 0; i < 4; ++i)
      #pragma unroll
      for (int j = 0; j < 2; ++j) acc[s][i][j] = (f32x4){0.f, 0.f, 0.f, 0.f};

  // ---- prologue: stage kt=0 (A0,B0 then A1,B1 — order matters for vmcnt) ----
  GLOAD16(aP[0], lds + dstOff);
  GLOAD16(bP[0], lds + 16384 + dstOff);
  GLOAD16(aP[1], lds + 8192 + dstOff);
  GLOAD16(bP[1], lds + 24576 + dstOff);

  // ---- main loop: all 4 next-tile loads staged at s0; counted vmcnt ----
  // s0-top: outstanding = 4 (kt's groups) -> vmcnt(2) completes A0B0(kt).
  // After staging 4 of kt+1: 6 in flight. s1-top: vmcnt(4) completes A1B1(kt),
  // leaves kt+1's 4 in flight (never drains until the tail). WAR safety: a
  // wave reaches s0-top(kt) only after issuing kt-1's MFMAs (ds_reads drained),
  // and writes into bufW are issued strictly after that barrier.
  for (int kt = 0; kt < NKT; ++kt) {
    char* bufR = lds + (kt & 1) * 32768;
    char* bufW = lds + ((kt + 1) & 1) * 32768;
    const int kos = (kt + 1) * 32;
    const bool st = (kt < NKT - 1);

    // phase s=0
    asm volatile("s_waitcnt vmcnt(2)" ::: "memory");   // A0,B0(kt) landed
    __builtin_amdgcn_s_barrier();
    if (st) {
      GLOAD16(aP[0] + kos, bufW + dstOff);
      GLOAD16(bP[0] + kos, bufW + 16384 + dstOff);
      GLOAD16(aP[1] + kos, bufW + 8192 + dstOff);
      GLOAD16(bP[1] + kos, bufW + 24576 + dstOff);
    }
    short8 af0[4], bf0[2];
    #pragma unroll
    for (int i = 0; i < 4; ++i) af0[i] = *(const short8*)(bufR + afOff[0][i]);
    #pragma unroll
    for (int j = 0; j < 2; ++j) bf0[j] = *(const short8*)(bufR + bfOff[0][j]);
    __builtin_amdgcn_s_setprio(1);
    #pragma unroll
    for (int i = 0; i < 4; ++i)
      #pragma unroll
      for (int j = 0; j < 2; ++j)
        acc[0][i][j] = __builtin_amdgcn_mfma_f32_16x16x32_bf16(af0[i], bf0[j],
                                                               acc[0][i][j], 0, 0, 0);
    __builtin_amdgcn_s_setprio(0);

    // phase s=1 (pure read+MFMA; stage already issued)
    if (st) asm volatile("s_waitcnt vmcnt(4)" ::: "memory");  // A1,B1(kt) landed
    else    asm volatile("s_waitcnt vmcnt(0)" ::: "memory");
    __builtin_amdgcn_s_barrier();
    short8 af1[4], bf1[2];
    #pragma unroll
    for (int i = 0; i < 4; ++i) af1[i] = *(const short8*)(bufR + afOff[1][i]);
    #pragma unroll
    for (int j = 0; j < 2; ++j) bf1[j] = *(const short8*)(bufR + bfOff[1][j]);
    __builtin_amdgcn_s_setprio(1);
    #pragma unroll
    for (int i = 0; i < 4; ++i)
      #pragma unroll
      for (int j = 0; j < 2; ++j)
        acc[1][i][j] = __builtin_amdgcn_mfma_f32_16x16x32_bf16(af1[i], bf1[j],
                                                               acc[1][i][j], 0, 0, 0);
    __builtin_amdgcn_s_setprio(0);
  }

  // ---- epilogue v3 (r12-proven): raw-stage once per row-half, single combine ----
  // zone layout: Lf[pl*Z1 + row*ZSTR + col], col in [0,128): even=re, odd=im.
  float* Lf = (float*)lds;
  float* outI = out + OUT_HALF;
  const int q = lane;                               // 0..63 (local q index)
  const float ang = (float)(nt * 64 + q) * 3.0679615757712823e-3f;   // pi*k/1024
  const float tr = cosf(ang), sn = sinf(ang);       // t = tr - i*sn
  const int rgrp = (lane >> 4) << 2;

  __syncthreads();   // all main-loop LDS reads complete before reuse

  #pragma unroll
  for (int h = 0; h < 2; ++h) {
    if (wr == h) {   // owner waves stage raw acc for rows [h*64, h*64+64)
      #pragma unroll
      for (int pl = 0; pl < 2; ++pl)
        #pragma unroll
        for (int i = 0; i < 4; ++i)
          #pragma unroll
          for (int j = 0; j < 2; ++j)
            #pragma unroll
            for (int r = 0; r < 4; ++r)
              Lf[pl * Z1 + (i * 16 + rgrp + r) * ZSTR + wc * 32 + j * 16 + fr]
                 = acc[pl][i][j][r];
    }
    __syncthreads();
    // combine + store: lane = q, 8 rows per iteration across the 8 waves
    #pragma unroll
    for (int it = 0; it < 8; ++it) {
      int row = wid + it * 8;                       // 0..63
      int gm  = M0 + h * 64 + row;
      if (gm < M_) {
        float2 y0 = *(const float2*)&Lf[row * ZSTR + 2 * q];
        float2 y1 = *(const float2*)&Lf[Z1 + row * ZSTR + 2 * q];
        float ur = tr * y1.x + sn * y1.y;           // Re(t*Y1)
        float ui = tr * y1.y - sn * y1.x;           // Im(t*Y1)
        size_t rb = (size_t)gm * KCH;
        if (nt == 0 && q == 0) {
          // cols 0,1 are the special real rows: Y[0] and Y[512]
          out [rb + 0]    = y0.x + y1.x;            // X[0] = Y0[0]+Y1[0]
          outI[rb + 0]    = 0.f;
          out [rb + 1024] = y0.x - y1.x;            // X[1024] = Y0[0]-Y1[0]
          outI[rb + 1024] = 0.f;
          out [rb + 512]  = y0.y;                   // X[512] = Y0[512] - i*Y1[512]
          outI[rb + 512]  = -y1.y;
        } else {
          int kq = nt * 64 + q;
          out [rb + kq]        = y0.x + ur;         // X[k]
          outI[rb + kq]        = y0.y + ui;
          out [rb + 1024 - kq] = y0.x - ur;         // X[1024-k] (conj pair)
          outI[rb + 1024 - kq] = -(y0.y - ui);
        }
      }
    }
    __syncthreads();   // zones reused by next row-half
  }
}

// ---------------- launcher ----------------
extern "C" void kernel_launch(void* const* d_in, const int* in_sizes, int n_in,
                              void* d_out, int out_size, void* d_ws, size_t ws_size,
                              hipStream_t stream) {
  const float* x = (const float*)d_in[0];
  float* out = (float*)d_out;

  short* pl0 = (short*)d_ws;                        // 64*81024 bf16
  short* pl1 = pl0 + (size_t)BC * PL;
  short* wb0 = pl1 + (size_t)BC * PL;               // 1024*1024
  short* wb1 = wb0 + (size_t)1024 * KD;             // total 24.9 MB

  prep_all<<<PREP_PLANE_BLOCKS + 1024, 256, 0, stream>>>(x, pl0, pl1, wb0, wb1);
  stft_gemm<<<NWG, 512, 0, stream>>>(pl0, pl1, wb0, wb1, out);
}

// Round 16
// 134.921 us; speedup vs baseline: 2.3726x; 1.0040x over previous
//
#include <hip/hip_runtime.h>

// ---------------- problem constants ----------------
#define B_     32
#define C_     2
#define L_     160000
#define HOP    512
#define PAD    1024
#define LPAD   162048            // L_ + 2*PAD
#define T_     313               // frames
#define BC     64                // B_*C_
#define M_     20032             // BC*T_
#define KCH    1025              // output channels per (real|imag)
#define OUT_HALF 20532800UL      // M_*KCH
#define PL     81024             // plane length per bc (LPAD/2)
#define KD     1024              // decimated K
#define NKT    32                // KD/32 K-tiles
#define NWG    1280              // 160*8 (24 dead blocks early-exit)
#define ZSTR   132               // epilogue zone row stride (words): 528B
#define Z1     8448              // zone-1 word offset: 64*132
#define PREP_PLANE_BLOCKS 2532   // prep grid split

typedef __attribute__((ext_vector_type(8))) short short8;
typedef __attribute__((ext_vector_type(4))) float f32x4;

static __device__ __forceinline__ short f2bf(float f) {
  union { float f; unsigned u; } v; v.f = f;
  unsigned u = v.u;
  unsigned r = (u + 0x7fffu + ((u >> 16) & 1u)) >> 16;  // RNE
  return (short)r;
}

// ---------------- fused prep: planes + weights in one launch ----------------
__global__ void prep_all(const float* __restrict__ x,
                         short* __restrict__ pl0, short* __restrict__ pl1,
                         short* __restrict__ wb0, short* __restrict__ wb1) {
  int b = blockIdx.x;
  if (b < PREP_PLANE_BLOCKS) {
    // ---- even/odd deinterleaved reflect-padded planes ----
    int v = b * 256 + threadIdx.x;                  // < 64*10128 = 648192
    int bc = v / 10128;
    int r  = v - bc * 10128;
    int p0 = r * 8;                                 // 8 p-positions -> 16 samples
    const float* src = x + (size_t)bc * L_;
    short8 e, o;
    if (r >= 64 && r <= 10000) {                    // fully interior
      int j0 = 16 * r - 1024;
      #pragma unroll
      for (int qq = 0; qq < 4; ++qq) {
        float4 f = *(const float4*)(src + j0 + qq * 4);
        e[qq * 2 + 0] = f2bf(f.x); o[qq * 2 + 0] = f2bf(f.y);
        e[qq * 2 + 1] = f2bf(f.z); o[qq * 2 + 1] = f2bf(f.w);
      }
    } else {
      #pragma unroll
      for (int u = 0; u < 16; ++u) {
        int j = 16 * r + u - 1024;
        j = j < 0 ? -j : j;
        j = j >= L_ ? 2 * L_ - 2 - j : j;
        short bb = f2bf(src[j]);
        if (u & 1) o[u >> 1] = bb; else e[u >> 1] = bb;
      }
    }
    *(short8*)&pl0[(size_t)bc * PL + p0] = e;
    *(short8*)&pl1[(size_t)bc * PL + p0] = o;
  } else {
    // ---- windowed DFT-1024 weights, interleaved re/im rows ----
    int id = (b - PREP_PLANE_BLOCKS) * 256 + threadIdx.x;  // < 262144
    int s   = id >> 17;
    int row = (id >> 7) & 1023;
    int n8  = (id & 127) * 8;
    int kp  = row >> 1, e = row & 1;
    short8 ov;
    #pragma unroll
    for (int u = 0; u < 8; ++u) {
      int n1 = n8 + u;
      float win = 0.5f - 0.5f * cosf((float)(2 * n1 + s) * 3.0679615757712823e-3f);
      float tw;
      if (e == 0)       tw = cosf((float)((n1 * kp) & 1023) * 6.1359231515425649e-3f);
      else if (kp == 0) tw = (n1 & 1) ? -1.0f : 1.0f;     // cos(pi*n1): re[512] row
      else              tw = -sinf((float)((n1 * kp) & 1023) * 6.1359231515425649e-3f);
      ov[u] = f2bf(win * tw);
    }
    short* wb = s ? wb1 : wb0;
    *(short8*)&wb[(size_t)row * KD + n8] = ov;
  }
}

// ---------------- GEMM: 128x128 tile, 512 thr, dual-plane acc, BK=32 ----------------
#define GLOAD16(g, l) __builtin_amdgcn_global_load_lds(                        \
    (const __attribute__((address_space(1))) void*)(g),                        \
    (__attribute__((address_space(3))) void*)(l), 16, 0, 0)

__global__ __launch_bounds__(512, 4) void stft_gemm(const short* __restrict__ pl0,
                                                    const short* __restrict__ pl1,
                                                    const short* __restrict__ wb0,
                                                    const short* __restrict__ wb1,
                                                    float* __restrict__ out) {
  // main loop: 2 buffers x (A0,A1,B0,B1 each [128][32] = 8KB) = 64KB
  // epilogue reuse: raw zones [2 planes][64 rows][132] fp32 = 67584 B
  __shared__ __align__(16) char lds[67584];
  const int tid  = threadIdx.x;
  const int lane = tid & 63;
  const int wid  = tid >> 6;          // 0..7

  // ---- XCD remap: 8 nt-blocks sharing an A-panel are consecutive ids with the
  // same id%8 -> same XCD -> A fetched ~once per panel; B (4MB) L2-resident.
  const int id = blockIdx.x;                   // 0..1279
  const int mt = (id & 7) * 20 + (id >> 6);    // 0..159
  if (mt >= 157) return;                       // dead-padded blocks: exit early
  const int nt = (id >> 3) & 7;
  const int M0 = mt * 128, N0 = nt * 128;

  // ---- staging: 1 instr per operand per plane; 512 threads cover [128][32] ----
  const int srow = tid >> 2;                                 // 0..127
  const int chunkSwz = ((tid & 3) ^ ((tid >> 3) & 3)) * 8;   // inverse-swizzled src
  const short* aP[2];
  const short* bP[2];
  {
    int m = M0 + srow; if (m > M_ - 1) m = M_ - 1;           // clamp (not stored)
    int bc = m / T_;
    int t  = m - bc * T_;
    size_t base = (size_t)bc * PL + (size_t)t * 256 + chunkSwz;
    aP[0] = pl0 + base;
    aP[1] = pl1 + base;
    size_t bb = (size_t)(N0 + srow) * KD + chunkSwz;
    bP[0] = wb0 + bb;
    bP[1] = wb1 + bb;
  }
  const int dstOff = tid * 16;   // linear LDS dest (waveBase + lane*16 invariant)

  // ---- fragment read offsets (proven conflict-free 64B-row XOR pattern) ----
  const int wr = wid >> 2, wc = wid & 3;    // 2m x 4n waves; per-wave 64x32
  const int fr = lane & 15;
  const int xorb = ((lane >> 4) * 16) ^ ((fr & 6) << 3);
  int afOff[2][4], bfOff[2][2];
  #pragma unroll
  for (int s = 0; s < 2; ++s) {
    #pragma unroll
    for (int i = 0; i < 4; ++i)
      afOff[s][i] = s * 8192 + (wr * 64 + i * 16 + fr) * 64 + xorb;
    #pragma unroll
    for (int j = 0; j < 2; ++j)
      bfOff[s][j] = 16384 + s * 8192 + (wc * 32 + j * 16 + fr) * 64 + xorb;
  }

  f32x4 acc[2][4][2];
  #pragma unroll
  for (int s = 0; s < 2; ++s)
    #pragma unroll
    for (int i = 0; i < 4; ++i)
      #pragma unroll
      for (int j = 0; j < 2; ++j) acc[s][i][j] = (f32x4){0.f, 0.f, 0.f, 0.f};

  // ---- prologue: stage kt=0 (A0,B0 then A1,B1 — order matters for vmcnt) ----
  GLOAD16(aP[0], lds + dstOff);
  GLOAD16(bP[0], lds + 16384 + dstOff);
  GLOAD16(aP[1], lds + 8192 + dstOff);
  GLOAD16(bP[1], lds + 24576 + dstOff);

  // ---- main loop: all 4 next-tile loads staged at s0; counted vmcnt ----
  // NO setprio: T5 is null-to-negative on lockstep 2-phase structures (m190);
  // it only pays on 8-phase role-split schedules (m218b). [r16 A/B]
  for (int kt = 0; kt < NKT; ++kt) {
    char* bufR = lds + (kt & 1) * 32768;
    char* bufW = lds + ((kt + 1) & 1) * 32768;
    const int kos = (kt + 1) * 32;
    const bool st = (kt < NKT - 1);

    // phase s=0
    asm volatile("s_waitcnt vmcnt(2)" ::: "memory");   // A0,B0(kt) landed
    __builtin_amdgcn_s_barrier();
    if (st) {
      GLOAD16(aP[0] + kos, bufW + dstOff);
      GLOAD16(bP[0] + kos, bufW + 16384 + dstOff);
      GLOAD16(aP[1] + kos, bufW + 8192 + dstOff);
      GLOAD16(bP[1] + kos, bufW + 24576 + dstOff);
    }
    short8 af0[4], bf0[2];
    #pragma unroll
    for (int i = 0; i < 4; ++i) af0[i] = *(const short8*)(bufR + afOff[0][i]);
    #pragma unroll
    for (int j = 0; j < 2; ++j) bf0[j] = *(const short8*)(bufR + bfOff[0][j]);
    #pragma unroll
    for (int i = 0; i < 4; ++i)
      #pragma unroll
      for (int j = 0; j < 2; ++j)
        acc[0][i][j] = __builtin_amdgcn_mfma_f32_16x16x32_bf16(af0[i], bf0[j],
                                                               acc[0][i][j], 0, 0, 0);

    // phase s=1 (pure read+MFMA; stage already issued)
    if (st) asm volatile("s_waitcnt vmcnt(4)" ::: "memory");  // A1,B1(kt) landed
    else    asm volatile("s_waitcnt vmcnt(0)" ::: "memory");
    __builtin_amdgcn_s_barrier();
    short8 af1[4], bf1[2];
    #pragma unroll
    for (int i = 0; i < 4; ++i) af1[i] = *(const short8*)(bufR + afOff[1][i]);
    #pragma unroll
    for (int j = 0; j < 2; ++j) bf1[j] = *(const short8*)(bufR + bfOff[1][j]);
    #pragma unroll
    for (int i = 0; i < 4; ++i)
      #pragma unroll
      for (int j = 0; j < 2; ++j)
        acc[1][i][j] = __builtin_amdgcn_mfma_f32_16x16x32_bf16(af1[i], bf1[j],
                                                               acc[1][i][j], 0, 0, 0);
  }

  // ---- epilogue v3 (r12-proven): raw-stage once per row-half, single combine ----
  // zone layout: Lf[pl*Z1 + row*ZSTR + col], col in [0,128): even=re, odd=im.
  float* Lf = (float*)lds;
  float* outI = out + OUT_HALF;
  const int q = lane;                               // 0..63 (local q index)
  const float ang = (float)(nt * 64 + q) * 3.0679615757712823e-3f;   // pi*k/1024
  const float tr = cosf(ang), sn = sinf(ang);       // t = tr - i*sn
  const int rgrp = (lane >> 4) << 2;

  __syncthreads();   // all main-loop LDS reads complete before reuse

  #pragma unroll
  for (int h = 0; h < 2; ++h) {
    if (wr == h) {   // owner waves stage raw acc for rows [h*64, h*64+64)
      #pragma unroll
      for (int pl = 0; pl < 2; ++pl)
        #pragma unroll
        for (int i = 0; i < 4; ++i)
          #pragma unroll
          for (int j = 0; j < 2; ++j)
            #pragma unroll
            for (int r = 0; r < 4; ++r)
              Lf[pl * Z1 + (i * 16 + rgrp + r) * ZSTR + wc * 32 + j * 16 + fr]
                 = acc[pl][i][j][r];
    }
    __syncthreads();
    // combine + store: lane = q, 8 rows per iteration across the 8 waves
    #pragma unroll
    for (int it = 0; it < 8; ++it) {
      int row = wid + it * 8;                       // 0..63
      int gm  = M0 + h * 64 + row;
      if (gm < M_) {
        float2 y0 = *(const float2*)&Lf[row * ZSTR + 2 * q];
        float2 y1 = *(const float2*)&Lf[Z1 + row * ZSTR + 2 * q];
        float ur = tr * y1.x + sn * y1.y;           // Re(t*Y1)
        float ui = tr * y1.y - sn * y1.x;           // Im(t*Y1)
        size_t rb = (size_t)gm * KCH;
        if (nt == 0 && q == 0) {
          // cols 0,1 are the special real rows: Y[0] and Y[512]
          out [rb + 0]    = y0.x + y1.x;            // X[0] = Y0[0]+Y1[0]
          outI[rb + 0]    = 0.f;
          out [rb + 1024] = y0.x - y1.x;            // X[1024] = Y0[0]-Y1[0]
          outI[rb + 1024] = 0.f;
          out [rb + 512]  = y0.y;                   // X[512] = Y0[512] - i*Y1[512]
          outI[rb + 512]  = -y1.y;
        } else {
          int kq = nt * 64 + q;
          out [rb + kq]        = y0.x + ur;         // X[k]
          outI[rb + kq]        = y0.y + ui;
          out [rb + 1024 - kq] = y0.x - ur;         // X[1024-k] (conj pair)
          outI[rb + 1024 - kq] = -(y0.y - ui);
        }
      }
    }
    __syncthreads();   // zones reused by next row-half
  }
}

// ---------------- launcher ----------------
extern "C" void kernel_launch(void* const* d_in, const int* in_sizes, int n_in,
                              void* d_out, int out_size, void* d_ws, size_t ws_size,
                              hipStream_t stream) {
  const float* x = (const float*)d_in[0];
  float* out = (float*)d_out;

  short* pl0 = (short*)d_ws;                        // 64*81024 bf16
  short* pl1 = pl0 + (size_t)BC * PL;
  short* wb0 = pl1 + (size_t)BC * PL;               // 1024*1024
  short* wb1 = wb0 + (size_t)1024 * KD;             // total 24.9 MB

  prep_all<<<PREP_PLANE_BLOCKS + 1024, 256, 0, stream>>>(x, pl0, pl1, wb0, wb1);
  stft_gemm<<<NWG, 512, 0, stream>>>(pl0, pl1, wb0, wb1, out);
}